// Round 11
// baseline (123.532 us; speedup 1.0000x reference)
//
#include <hip/hip_runtime.h>

// out = A @ x, COO (rows sorted), E=800000, N=50000, D=128.
// R19: counted-vmcnt ring pipeline (T4). History: agg ~44-47 us across 7
// structural variants; R16 ablation: gather 21 us + skeleton 17 us,
// SERIALIZED. R17 (source batch): compiler sank it (VGPR=44). R18 (64-wide
// asm batch + vmcnt(0) drain): spilled (VGPR=56) and drain-to-zero is the
// null T3 pattern -> 57-62 us. This round is the guide's actual lever:
// counted vmcnt, never 0 in the loop (m135: vmcnt(N) waits for the oldest
// outstanding; m218: counted vs drain0 = +38-73%).
//  - 16-slot register ring of inline-asm SADDR gathers (volatile = issue
//    order). Prologue: issue 0..15.
//  - steady j=0..47: s_waitcnt vmcnt(15) [load j retired, in-order] ->
//    sched_barrier(0) [rule #18] -> consume j (FMA + R17 pending slots,
//    stores deferred) -> issue j+16 into slot j&15.
//  - tail: vmcnt(0), consume 48..63. Phase 2: flush pendings (first/final
//    segment atomic, interior NT) -- proven ownership logic.
// Interleaved overflow stores only make vmcnt(15) stricter (safe).
// ~65 VGPR: no spill. EPW=64, 12500 waves. prep unchanged.

#define D_FEAT 128
#define EPW 64            // edges per wave
#define WAVES_PER_BLOCK 4
#define BLOCK_THREADS 256
#define PF 8              // fallback path prefetch

typedef float v2f __attribute__((ext_vector_type(2)));

__device__ __forceinline__ float bcast_f(float v, int j) {
    return __int_as_float(__builtin_amdgcn_readlane(__float_as_int(v), j));
}

__device__ __forceinline__ unsigned short f2bf_rne(float f) {
    unsigned int b = __float_as_uint(f);
    b += 0x7fffu + ((b >> 16) & 1u);
    return (unsigned short)(b >> 16);
}

// prep: zero out + x fp32->bf16 (linear) + pack (col<<16)|bf16(val).
__global__ __launch_bounds__(256) void prep_kernel(
    const float* __restrict__ x, const float* __restrict__ vals,
    const int* __restrict__ cols, unsigned short* __restrict__ xb,
    unsigned int* __restrict__ cv, float* __restrict__ out,
    int n4, int n_edges, int n_out4) {
    const int tid = blockIdx.x * blockDim.x + threadIdx.x;
    const int nth = gridDim.x * blockDim.x;
    float4 z = make_float4(0.f, 0.f, 0.f, 0.f);
    float4* __restrict__ oz = (float4*)out;
    for (int i = tid; i < n_out4; i += nth) oz[i] = z;
    const float4* __restrict__ x4 = (const float4*)x;
    ushort4* __restrict__ o4 = (ushort4*)xb;
    for (int i = tid; i < n4; i += nth) {
        float4 f = x4[i];
        ushort4 o;
        o.x = f2bf_rne(f.x);
        o.y = f2bf_rne(f.y);
        o.z = f2bf_rne(f.z);
        o.w = f2bf_rne(f.w);
        o4[i] = o;
    }
    for (int e = tid; e < n_edges; e += nth) {
        cv[e] = ((unsigned int)cols[e] << 16) | (unsigned int)f2bf_rne(vals[e]);
    }
}

__global__ __launch_bounds__(BLOCK_THREADS, 4) void agg_pipe_kernel(
    const unsigned int* __restrict__ xb,  // [N][64] uints, 2 bf16 each
    const unsigned int* __restrict__ cv,  // [E] packed (col<<16)|bf16(val)
    const int* __restrict__ rows, float* __restrict__ out, int n_edges) {
    const int wave = blockIdx.x * WAVES_PER_BLOCK + (threadIdx.x >> 6);
    const int lane = threadIdx.x & 63;

    const int start = wave * EPW;
    if (start >= n_edges) return;   // E % 64 == 0 by host guard

    const unsigned int mycv = __builtin_nontemporal_load(cv + start + lane);
    const int myr = __builtin_nontemporal_load(rows + start + lane);
    const int nxt = __shfl(myr, (lane + 1) & 63);
    const unsigned long long bmask =
        __ballot(myr != nxt) & 0x7fffffffffffffffULL;  // bit63 = span end
    const int first_row = __builtin_amdgcn_readfirstlane(myr);

    const unsigned int lb = lane << 2;  // lane byte offset within the row
    unsigned int xu[16];                // 16-slot gather ring

    // -------- prologue: issue loads 0..15 (issue-ordered volatile asm) ----
#pragma unroll
    for (int t = 0; t < 16; ++t) {
        const unsigned int sv =
            (unsigned int)__builtin_amdgcn_readlane((int)mycv, t);
        const unsigned int off = ((sv >> 16) << 8) + lb;  // node*256 + lane*4
        asm volatile("global_load_dword %0, %1, %2"
                     : "=v"(xu[t])
                     : "v"(off), "s"(xb));
    }

    // -------- consume state: acc + 8 register pending slots ---------------
    float accx = 0.f, accy = 0.f;
    int cur_row = first_row;
    auto flush_vals = [&](int fr, float ax, float ay) {
        float* o = out + (size_t)fr * D_FEAT + 2 * lane;
        if (fr == first_row) {
            atomicAdd(o, ax);
            atomicAdd(o + 1, ay);
        } else {
            v2f st; st.x = ax; st.y = ay;
            __builtin_nontemporal_store(st, (v2f*)o);
        }
    };
    int pc = 0;
    int pr0 = 0, pr1 = 0, pr2 = 0, pr3 = 0, pr4 = 0, pr5 = 0, pr6 = 0, pr7 = 0;
    float p0x = 0.f, p0y = 0.f, p1x = 0.f, p1y = 0.f, p2x = 0.f, p2y = 0.f,
          p3x = 0.f, p3y = 0.f, p4x = 0.f, p4y = 0.f, p5x = 0.f, p5y = 0.f,
          p6x = 0.f, p6y = 0.f, p7x = 0.f, p7y = 0.f;

    auto consume = [&](int t, unsigned int xv) {
        const unsigned int sv =
            (unsigned int)__builtin_amdgcn_readlane((int)mycv, t);
        const float vf = __uint_as_float(sv << 16);  // bf16 val, high half
        accx = fmaf(vf, __uint_as_float(xv << 16), accx);
        accy = fmaf(vf, __uint_as_float(xv & 0xffff0000u), accy);
        if (t < 63) {
            if ((bmask >> t) & 1ULL) {  // row ends at edge t (wave-uniform)
                if      (pc == 0) { pr0 = cur_row; p0x = accx; p0y = accy; }
                else if (pc == 1) { pr1 = cur_row; p1x = accx; p1y = accy; }
                else if (pc == 2) { pr2 = cur_row; p2x = accx; p2y = accy; }
                else if (pc == 3) { pr3 = cur_row; p3x = accx; p3y = accy; }
                else if (pc == 4) { pr4 = cur_row; p4x = accx; p4y = accy; }
                else if (pc == 5) { pr5 = cur_row; p5x = accx; p5y = accy; }
                else if (pc == 6) { pr6 = cur_row; p6x = accx; p6y = accy; }
                else if (pc == 7) { pr7 = cur_row; p7x = accx; p7y = accy; }
                else              { flush_vals(cur_row, accx, accy); }
                ++pc;
                accx = 0.f; accy = 0.f;
                cur_row = __builtin_amdgcn_readlane(myr, t + 1);
            }
        }
    };

    // -------- steady state: wait-oldest, consume j, issue j+16 ------------
#pragma unroll
    for (int j = 0; j < 48; ++j) {
        asm volatile("s_waitcnt vmcnt(15)" ::: "memory");
        __builtin_amdgcn_sched_barrier(0);  // rule #18
        consume(j, xu[j & 15]);
        const unsigned int sv2 =
            (unsigned int)__builtin_amdgcn_readlane((int)mycv, j + 16);
        const unsigned int off2 = ((sv2 >> 16) << 8) + lb;
        asm volatile("global_load_dword %0, %1, %2"
                     : "=v"(xu[j & 15])
                     : "v"(off2), "s"(xb));
    }
    // -------- tail: drain, consume 48..63 ---------------------------------
    asm volatile("s_waitcnt vmcnt(0)" ::: "memory");
    __builtin_amdgcn_sched_barrier(0);
#pragma unroll
    for (int j = 48; j < 64; ++j) consume(j, xu[j & 15]);

    // -------- phase 2: flush pendings, then the final (shared) segment ----
    if (pc > 0) flush_vals(pr0, p0x, p0y);
    if (pc > 1) flush_vals(pr1, p1x, p1y);
    if (pc > 2) flush_vals(pr2, p2x, p2y);
    if (pc > 3) flush_vals(pr3, p3x, p3y);
    if (pc > 4) flush_vals(pr4, p4x, p4y);
    if (pc > 5) flush_vals(pr5, p5x, p5y);
    if (pc > 6) flush_vals(pr6, p6x, p6y);
    if (pc > 7) flush_vals(pr7, p7x, p7y);
    // Final row of the span: possibly shared with the next wave -> atomic.
    {
        float* o = out + (size_t)cur_row * D_FEAT + 2 * lane;
        atomicAdd(o, accx);
        atomicAdd(o + 1, accy);
    }
}

// Fallback (R3-proven fp32 atomic path) for unexpected shapes / small ws.
__global__ __launch_bounds__(BLOCK_THREADS) void agg_f32_kernel(
    const float* __restrict__ x, const float* __restrict__ vals,
    const int* __restrict__ rows, const int* __restrict__ cols,
    float* __restrict__ out, int n_edges, int epw) {
    const int wave = blockIdx.x * WAVES_PER_BLOCK + (threadIdx.x >> 6);
    const int lane = threadIdx.x & 63;

    const int start = wave * epw;
    if (start >= n_edges) return;
    int end = start + epw;
    if (end > n_edges) end = n_edges;

    const float2* __restrict__ x2 = (const float2*)x;
    const int first_row = rows[start];
    const int last_row  = rows[end - 1];

    float2 acc = make_float2(0.f, 0.f);
    int cur_row = first_row;

    for (int e0 = start; e0 < end; e0 += 64) {
        const int nb = min(end - e0, 64);
        int myc = 0, myr = 0;
        float myv = 0.f;
        if (lane < nb) {
            myc = cols[e0 + lane];
            myr = rows[e0 + lane];
            myv = vals[e0 + lane];
        }
        for (int j0 = 0; j0 < nb; j0 += PF) {
            const int m = min(nb - j0, PF);
            float2 xv[PF];
            int    rj[PF];
            float  vj[PF];
#pragma unroll
            for (int t = 0; t < PF; ++t) {
                if (t < m) {
                    const int cj = __builtin_amdgcn_readlane(myc, j0 + t);
                    rj[t] = __builtin_amdgcn_readlane(myr, j0 + t);
                    vj[t] = bcast_f(myv, j0 + t);
                    xv[t] = x2[(size_t)cj * (D_FEAT / 2) + lane];
                }
            }
#pragma unroll
            for (int t = 0; t < PF; ++t) {
                if (t < m) {
                    if (rj[t] != cur_row) {
                        float* o = out + (size_t)cur_row * D_FEAT + 2 * lane;
                        if (cur_row == first_row || cur_row == last_row) {
                            atomicAdd(o,     acc.x);
                            atomicAdd(o + 1, acc.y);
                        } else {
                            v2f st; st.x = acc.x; st.y = acc.y;
                            __builtin_nontemporal_store(st, (v2f*)o);
                        }
                        acc.x = 0.f; acc.y = 0.f;
                        cur_row = rj[t];
                    }
                    acc.x = fmaf(vj[t], xv[t].x, acc.x);
                    acc.y = fmaf(vj[t], xv[t].y, acc.y);
                }
            }
        }
    }
    float* o = out + (size_t)cur_row * D_FEAT + 2 * lane;
    atomicAdd(o,     acc.x);
    atomicAdd(o + 1, acc.y);
}

extern "C" void kernel_launch(void* const* d_in, const int* in_sizes, int n_in,
                              void* d_out, int out_size, void* d_ws, size_t ws_size,
                              hipStream_t stream) {
    const float* x    = (const float*)d_in[0];
    const float* vals = (const float*)d_in[1];
    const int*   rows = (const int*)d_in[2];
    const int*   cols = (const int*)d_in[3];
    float*       out  = (float*)d_out;

    const int n_edges = in_sizes[1];
    const int n_x     = in_sizes[0];          // N*D floats
    const int n_nodes = out_size / D_FEAT;    // N

    const size_t xb_bytes = (size_t)n_x * sizeof(unsigned short);
    const size_t cv_off   = (xb_bytes + 255) & ~(size_t)255;
    const size_t need     = cv_off + (size_t)n_edges * sizeof(unsigned int);

    const bool fast_ok = (ws_size >= need) && (n_edges % 64 == 0) &&
                         (n_nodes <= 65536) && (n_x % 4 == 0) &&
                         (out_size % 4 == 0) && (n_x == n_nodes * D_FEAT);

    if (fast_ok) {
        unsigned short* xb = (unsigned short*)d_ws;
        unsigned int*   cv = (unsigned int*)((char*)d_ws + cv_off);
        prep_kernel<<<2048, 256, 0, stream>>>(x, vals, cols, xb, cv, out,
                                              n_x / 4, n_edges, out_size / 4);
        const int waves  = (n_edges + EPW - 1) / EPW;
        const int blocks = (waves + WAVES_PER_BLOCK - 1) / WAVES_PER_BLOCK;
        agg_pipe_kernel<<<blocks, BLOCK_THREADS, 0, stream>>>(
            (const unsigned int*)xb, cv, rows, out, n_edges);
    } else {
        (void)hipMemsetAsync(d_out, 0, (size_t)out_size * sizeof(float), stream);
        const int total_waves = 8192;
        const int epw    = (n_edges + total_waves - 1) / total_waves;
        const int blocks = total_waves / WAVES_PER_BLOCK;
        agg_f32_kernel<<<blocks, BLOCK_THREADS, 0, stream>>>(
            x, vals, rows, cols, out, n_edges, epw);
    }
}

// Round 12
// 118.194 us; speedup vs baseline: 1.0452x; 1.0452x over previous
//
#include <hip/hip_runtime.h>

// out = A @ x, COO (rows sorted), E=800000, N=50000, D=128.
// R20: FINAL — revert to the best-measured configuration (R11, 118.3 us).
// Session findings (R9-R19, 9 structural agg variants + 1 ablation):
//  - agg ~44-47 us is invariant to: gather placement (row-major / addr-sliced
//    / L2-resident slice-major), nominal MLP (2..16), VMEM instr count (2x),
//    forced asm batching (64-wide, spilled), counted-vmcnt 16-ring (WORSE:
//    queueing at 64% occupancy).
//  - R16 ablation: gather ~21 us + skeleton ~17 us; their "sum" behavior is
//    contention for the same L2<->fabric pipe: FETCH 75 + WRITE 34 MB at the
//    measured ~3.3 TB/s random-access fabric/L3 rate = ~33 us floor.
//  - L2 table residency is defeated by streaming metadata/out traffic
//    evicting the slice even with nt hints (R12/R13 flat).
//  - fp8 table would halve gather bytes but ~16x the absmax (risk).
// Structure: prep (zero out + fp32->bf16 + (col<<16)|bf16(val) pack) + agg
// (wave owns 128 edges; ballot flush bitmask; readlane (col,val) broadcast;
// 2 bf16 dims/lane fp32 acc; interior rows NT-stored by sole writer;
// first/final rows of the wave range atomicAdd onto zeroed out).

#define D_FEAT 128
#define EPW 128           // edges per wave (multiple of 64)
#define WAVES_PER_BLOCK 4
#define BLOCK_THREADS 256
#define PF 16             // gathers in flight per chunk

typedef float v2f __attribute__((ext_vector_type(2)));

__device__ __forceinline__ float bcast_f(float v, int j) {
    return __int_as_float(__builtin_amdgcn_readlane(__float_as_int(v), j));
}

__device__ __forceinline__ unsigned short f2bf_rne(float f) {
    unsigned int b = __float_as_uint(f);
    b += 0x7fffu + ((b >> 16) & 1u);
    return (unsigned short)(b >> 16);
}

// prep: zero out + x fp32->bf16 + pack (col<<16)|bf16(val).
__global__ __launch_bounds__(256) void prep_kernel(
    const float* __restrict__ x, const float* __restrict__ vals,
    const int* __restrict__ cols, unsigned short* __restrict__ xb,
    unsigned int* __restrict__ cv, float* __restrict__ out,
    int n4, int n_edges, int n_out4) {
    const int tid = blockIdx.x * blockDim.x + threadIdx.x;
    const int nth = gridDim.x * blockDim.x;
    // (a) zero the output (replaces hipMemsetAsync dispatch)
    float4 z = make_float4(0.f, 0.f, 0.f, 0.f);
    float4* __restrict__ oz = (float4*)out;
    for (int i = tid; i < n_out4; i += nth) oz[i] = z;
    // (b) x fp32 -> bf16 (RNE), float4 -> ushort4
    const float4* __restrict__ x4 = (const float4*)x;
    ushort4* __restrict__ o4 = (ushort4*)xb;
    for (int i = tid; i < n4; i += nth) {
        float4 f = x4[i];
        ushort4 o;
        o.x = f2bf_rne(f.x);
        o.y = f2bf_rne(f.y);
        o.z = f2bf_rne(f.z);
        o.w = f2bf_rne(f.w);
        o4[i] = o;
    }
    // (c) pack (col<<16) | bf16(val)
    for (int e = tid; e < n_edges; e += nth) {
        cv[e] = ((unsigned int)cols[e] << 16) | (unsigned int)f2bf_rne(vals[e]);
    }
}

__global__ __launch_bounds__(BLOCK_THREADS) void agg_bf16_kernel(
    const unsigned int* __restrict__ xb,  // [N][64] uints, 2 bf16 each
    const unsigned int* __restrict__ cv,  // [E] packed (col<<16)|bf16(val)
    const int* __restrict__ rows, float* __restrict__ out, int n_edges) {
    const int wave = blockIdx.x * WAVES_PER_BLOCK + (threadIdx.x >> 6);
    const int lane = threadIdx.x & 63;

    const int start = wave * EPW;
    if (start >= n_edges) return;
    const int end = min(start + EPW, n_edges);  // multiple of 64 by host guard

    const int first_row = rows[start];  // wave-uniform broadcast load
    float2 acc = make_float2(0.f, 0.f);
    int cur_row = first_row;

    for (int e0 = start; e0 < end; e0 += 64) {
        const unsigned int mycv = __builtin_nontemporal_load(cv + e0 + lane);
        const int myr = __builtin_nontemporal_load(rows + e0 + lane);
        const int nxt = __shfl(myr, (lane + 1) & 63);
        const unsigned long long bmask =
            __ballot(myr != nxt) & 0x7fffffffffffffffULL;  // bit63 handled at
                                                           // next group start
        const int g0 = __builtin_amdgcn_readfirstlane(myr);
        if (g0 != cur_row) {  // cur_row's last edge was previous group's #63
            float* o = out + (size_t)cur_row * D_FEAT + 2 * lane;
            if (cur_row == first_row) {
                atomicAdd(o, acc.x);
                atomicAdd(o + 1, acc.y);
            } else {
                v2f st; st.x = acc.x; st.y = acc.y;
                __builtin_nontemporal_store(st, (v2f*)o);
            }
            acc.x = 0.f; acc.y = 0.f;
            cur_row = g0;
        }
#pragma unroll
        for (int j0 = 0; j0 < 64; j0 += PF) {
            unsigned int sv[PF];
            unsigned int xu[PF];
#pragma unroll
            for (int t = 0; t < PF; ++t) {  // issue PF independent gathers
                sv[t] = (unsigned int)__builtin_amdgcn_readlane((int)mycv, j0 + t);
                xu[t] = xb[(size_t)(sv[t] >> 16) * (D_FEAT / 2) + lane];
            }
#pragma unroll
            for (int t = 0; t < PF; ++t) {
                const float vf = __uint_as_float(sv[t] << 16);  // bf16 val
                acc.x = fmaf(vf, __uint_as_float(xu[t] << 16), acc.x);
                acc.y = fmaf(vf, __uint_as_float(xu[t] & 0xffff0000u), acc.y);
                if ((bmask >> (j0 + t)) & 1ULL) {  // row ends at this edge
                    const int fr = __builtin_amdgcn_readlane(myr, j0 + t);
                    float* o = out + (size_t)fr * D_FEAT + 2 * lane;
                    if (fr == first_row) {
                        atomicAdd(o, acc.x);
                        atomicAdd(o + 1, acc.y);
                    } else {
                        v2f st; st.x = acc.x; st.y = acc.y;
                        __builtin_nontemporal_store(st, (v2f*)o);
                    }
                    acc.x = 0.f; acc.y = 0.f;
                }
            }
        }
        cur_row = __builtin_amdgcn_readlane(myr, 63);
    }
    // Final row of the range: possibly shared with the next wave -> atomic.
    float* o = out + (size_t)cur_row * D_FEAT + 2 * lane;
    atomicAdd(o, acc.x);
    atomicAdd(o + 1, acc.y);
}

// Fallback (R3-proven fp32 atomic path) for unexpected shapes / small ws.
__global__ __launch_bounds__(BLOCK_THREADS) void agg_f32_kernel(
    const float* __restrict__ x, const float* __restrict__ vals,
    const int* __restrict__ rows, const int* __restrict__ cols,
    float* __restrict__ out, int n_edges, int epw) {
    const int wave = blockIdx.x * WAVES_PER_BLOCK + (threadIdx.x >> 6);
    const int lane = threadIdx.x & 63;

    const int start = wave * epw;
    if (start >= n_edges) return;
    int end = start + epw;
    if (end > n_edges) end = n_edges;

    const float2* __restrict__ x2 = (const float2*)x;
    const int first_row = rows[start];
    const int last_row  = rows[end - 1];

    float2 acc = make_float2(0.f, 0.f);
    int cur_row = first_row;

    for (int e0 = start; e0 < end; e0 += 64) {
        const int nb = min(end - e0, 64);
        int myc = 0, myr = 0;
        float myv = 0.f;
        if (lane < nb) {
            myc = cols[e0 + lane];
            myr = rows[e0 + lane];
            myv = vals[e0 + lane];
        }
        for (int j0 = 0; j0 < nb; j0 += 8) {
            const int m = min(nb - j0, 8);
            float2 xv[8];
            int    rj[8];
            float  vj[8];
#pragma unroll
            for (int t = 0; t < 8; ++t) {
                if (t < m) {
                    const int cj = __builtin_amdgcn_readlane(myc, j0 + t);
                    rj[t] = __builtin_amdgcn_readlane(myr, j0 + t);
                    vj[t] = bcast_f(myv, j0 + t);
                    xv[t] = x2[(size_t)cj * (D_FEAT / 2) + lane];
                }
            }
#pragma unroll
            for (int t = 0; t < 8; ++t) {
                if (t < m) {
                    if (rj[t] != cur_row) {
                        float* o = out + (size_t)cur_row * D_FEAT + 2 * lane;
                        if (cur_row == first_row || cur_row == last_row) {
                            atomicAdd(o,     acc.x);
                            atomicAdd(o + 1, acc.y);
                        } else {
                            v2f st; st.x = acc.x; st.y = acc.y;
                            __builtin_nontemporal_store(st, (v2f*)o);
                        }
                        acc.x = 0.f; acc.y = 0.f;
                        cur_row = rj[t];
                    }
                    acc.x = fmaf(vj[t], xv[t].x, acc.x);
                    acc.y = fmaf(vj[t], xv[t].y, acc.y);
                }
            }
        }
    }
    float* o = out + (size_t)cur_row * D_FEAT + 2 * lane;
    atomicAdd(o,     acc.x);
    atomicAdd(o + 1, acc.y);
}

extern "C" void kernel_launch(void* const* d_in, const int* in_sizes, int n_in,
                              void* d_out, int out_size, void* d_ws, size_t ws_size,
                              hipStream_t stream) {
    const float* x    = (const float*)d_in[0];
    const float* vals = (const float*)d_in[1];
    const int*   rows = (const int*)d_in[2];
    const int*   cols = (const int*)d_in[3];
    float*       out  = (float*)d_out;

    const int n_edges = in_sizes[1];
    const int n_x     = in_sizes[0];          // N*D floats
    const int n_nodes = out_size / D_FEAT;    // N

    const size_t xb_bytes = (size_t)n_x * sizeof(unsigned short);
    const size_t cv_off   = (xb_bytes + 255) & ~(size_t)255;
    const size_t need     = cv_off + (size_t)n_edges * sizeof(unsigned int);

    const bool fast_ok = (ws_size >= need) && (n_edges % 64 == 0) &&
                         (n_nodes <= 65536) && (n_x % 4 == 0) &&
                         (out_size % 4 == 0) && (n_x == n_nodes * D_FEAT);

    if (fast_ok) {
        unsigned short* xb = (unsigned short*)d_ws;
        unsigned int*   cv = (unsigned int*)((char*)d_ws + cv_off);
        prep_kernel<<<2048, 256, 0, stream>>>(x, vals, cols, xb, cv, out,
                                              n_x / 4, n_edges, out_size / 4);
        const int waves  = (n_edges + EPW - 1) / EPW;
        const int blocks = (waves + WAVES_PER_BLOCK - 1) / WAVES_PER_BLOCK;
        agg_bf16_kernel<<<blocks, BLOCK_THREADS, 0, stream>>>(
            (const unsigned int*)xb, cv, rows, out, n_edges);
    } else {
        (void)hipMemsetAsync(d_out, 0, (size_t)out_size * sizeof(float), stream);
        const int total_waves = 8192;
        const int epw    = (n_edges + total_waves - 1) / total_waves;
        const int blocks = total_waves / WAVES_PER_BLOCK;
        agg_f32_kernel<<<blocks, BLOCK_THREADS, 0, stream>>>(
            x, vals, rows, cols, out, n_edges, epw);
    }
}